// Round 1
// baseline (1637.945 us; speedup 1.0000x reference)
//
#include <hip/hip_runtime.h>
#include <math.h>

#define BB 128
#define TT 1024
#define DD 128
#define HH 64
#define G3 192   // 3*H
#define KK 32

// ---------------------------------------------------------------------------
// Kernel 1: xproj[B*T,192] = X[B*T,128] @ Wk[128,192] + b0
// block = 192 threads (thread j owns Wk column j in regs), 32 rows per block
// ---------------------------------------------------------------------------
#define XP_ROWS 32
__global__ __launch_bounds__(192) void xproj_kernel(const float* __restrict__ X,
                                                    const float* __restrict__ Wk,
                                                    const float* __restrict__ gbias,
                                                    float* __restrict__ xp) {
    __shared__ float Xs[XP_ROWS * DD];
    const int j = threadIdx.x;                 // 0..191
    const int row0 = blockIdx.x * XP_ROWS;
    for (int idx = j; idx < XP_ROWS * DD; idx += G3)
        Xs[idx] = X[(size_t)row0 * DD + idx];
    float wcol[DD];
#pragma unroll
    for (int d = 0; d < DD; ++d) wcol[d] = Wk[d * G3 + j];
    const float b0 = gbias[j];                 // gru_bias[0][j]
    __syncthreads();
#pragma unroll 1
    for (int r = 0; r < XP_ROWS; ++r) {
        float acc = 0.f;
#pragma unroll
        for (int d = 0; d < DD; d += 4) {
            float4 xv = *(const float4*)&Xs[r * DD + d];
            acc += xv.x * wcol[d] + xv.y * wcol[d + 1] + xv.z * wcol[d + 2] + xv.w * wcol[d + 3];
        }
        xp[((size_t)row0 + r) * G3 + j] = acc + b0;
    }
}

// ---------------------------------------------------------------------------
// Kernel 2: seq_len[b] = sum(mask[b,:]); also copies chain_kernel to d_out
// ---------------------------------------------------------------------------
__global__ __launch_bounds__(256) void seqlen_kernel(const int* __restrict__ mask,
                                                     const float* __restrict__ chain,
                                                     float* __restrict__ out_seqlen,
                                                     float* __restrict__ out_chain,
                                                     int* __restrict__ ws_seqlen) {
    const int b = blockIdx.x;
    const int tid = threadIdx.x;
    int s = 0;
    for (int t = tid; t < TT; t += 256) s += mask[b * TT + t];
#pragma unroll
    for (int off = 32; off >= 1; off >>= 1) s += __shfl_down(s, off, 64);
    __shared__ int red[4];
    if ((tid & 63) == 0) red[tid >> 6] = s;
    __syncthreads();
    if (tid == 0) {
        int tot = red[0] + red[1] + red[2] + red[3];
        out_seqlen[b] = (float)tot;
        ws_seqlen[b] = tot;
    }
    if (b == 0) {
        for (int i = tid; i < KK * KK; i += 256) out_chain[i] = chain[i];
    }
}

// ---------------------------------------------------------------------------
// Kernel 3: GRU scan. One block per batch element, 192 threads.
// Thread j holds Wr[:,j] (64 VGPRs); h broadcast through LDS.
// ---------------------------------------------------------------------------
__global__ __launch_bounds__(192) void gru_kernel(const float* __restrict__ xp,
                                                  const float* __restrict__ Wr,
                                                  const float* __restrict__ gbias,
                                                  const int* __restrict__ mask,
                                                  float* __restrict__ hidden) {
    const int b = blockIdx.x;
    const int j = threadIdx.x;                 // 0..191
    __shared__ float h[HH];
    __shared__ float gbuf[4 * HH];             // z | r | rh | xh
    __shared__ int mrow[TT];
    float wr[HH];
#pragma unroll
    for (int i = 0; i < HH; ++i) wr[i] = Wr[i * G3 + j];
    const float b1 = gbias[G3 + j];            // gru_bias[1][j]
    for (int idx = j; idx < TT; idx += G3) mrow[idx] = mask[b * TT + idx];
    if (j < HH) h[j] = 0.f;
    __syncthreads();
    const float* xpb = xp + (size_t)b * TT * G3;
    float xv_next = xpb[j];
    for (int t = 0; t < TT; ++t) {
        float xv = xv_next;
        if (t + 1 < TT) xv_next = xpb[(size_t)(t + 1) * G3 + j];
        float rec = b1;
#pragma unroll
        for (int i = 0; i < HH; i += 4) {
            float4 hv = *(const float4*)&h[i];
            rec += hv.x * wr[i] + hv.y * wr[i + 1] + hv.z * wr[i + 2] + hv.w * wr[i + 3];
        }
        if (j < 2 * HH) {
            gbuf[j] = 1.f / (1.f + __expf(-(xv + rec)));   // z (j<64), r (64..127)
        } else {
            gbuf[j] = rec;                                  // rh at [128..191]
            gbuf[j + HH] = xv;                              // xh at [192..255]
        }
        __syncthreads();
        if (j < HH) {
            float z  = gbuf[j];
            float r  = gbuf[HH + j];
            float rh = gbuf[2 * HH + j];
            float xh = gbuf[3 * HH + j];
            float hh = tanhf(xh + r * rh);
            float hp = h[j];
            float hn = z * hp + (1.f - z) * hh;
            if (mrow[t] == 0) hn = hp;                      // masked step carries state
            h[j] = hn;
            hidden[((size_t)b * TT + t) * HH + j] = hn;
        }
        __syncthreads();
    }
}

// ---------------------------------------------------------------------------
// Kernel 4: potentials[row,k] = hidden[row,:]@Dk[:,k] + db[k] (+ boundaries)
// ---------------------------------------------------------------------------
#define PR 8
__global__ __launch_bounds__(256) void pot_kernel(const float* __restrict__ hidden,
                                                  const float* __restrict__ Dk,
                                                  const float* __restrict__ db,
                                                  const float* __restrict__ lb,
                                                  const float* __restrict__ rb,
                                                  const int* __restrict__ slen,
                                                  float* __restrict__ pot) {
    __shared__ float Hs[PR * HH];
    __shared__ float Dks[HH * KK];
    const int tid = threadIdx.x;
    const int k = tid & (KK - 1);
    const int rl = tid >> 5;                   // 0..7
    const size_t row0 = (size_t)blockIdx.x * PR;
    for (int idx = tid; idx < PR * HH; idx += 256) Hs[idx] = hidden[row0 * HH + idx];
    for (int idx = tid; idx < HH * KK; idx += 256) Dks[idx] = Dk[idx];
    __syncthreads();
    float acc = db[k];
#pragma unroll
    for (int i = 0; i < HH; i += 4) {
        float4 hv = *(const float4*)&Hs[rl * HH + i];
        acc += hv.x * Dks[i * KK + k] + hv.y * Dks[(i + 1) * KK + k]
             + hv.z * Dks[(i + 2) * KK + k] + hv.w * Dks[(i + 3) * KK + k];
    }
    const size_t row = row0 + rl;
    const int t = (int)(row & (TT - 1));
    const int bb = (int)(row >> 10);
    if (t == 0) acc += lb[k];
    if (t == slen[bb] - 1) acc += rb[k];
    pot[row * KK + k] = acc;
}

// ---------------------------------------------------------------------------
// Kernel 5: Viterbi. One block per batch; forward on wave 0 (registers+shfl),
// bp as uint8 in LDS; chunked parallel backtrack.
// ---------------------------------------------------------------------------
__global__ __launch_bounds__(256) void viterbi_kernel(const float* __restrict__ pot,
                                                      const float* __restrict__ chain,
                                                      float* __restrict__ decoded) {
    const int b = blockIdx.x;
    const int tid = threadIdx.x;
    __shared__ unsigned char bp[(TT - 1) * KK];        // 32736 B
    __shared__ unsigned char table[32 * 32 * KK];      // 32 chunks x 32 pos x 32 cand
    __shared__ int ent[32];
    __shared__ int last_tag_s;
    const float* pb = pot + (size_t)b * TT * KK;

    if (tid < 64) {
        const int k = tid & 31;
        const int hf = tid >> 5;                       // half: k_from in [16h,16h+16)
        float ccol[16];
#pragma unroll
        for (int m = 0; m < 16; ++m) ccol[m] = chain[(hf * 16 + m) * KK + k];
        float s = pb[k];                               // score init = pots[0]
        float pv_next = pb[KK + k];
        for (int t = 1; t < TT; ++t) {
            float pv = pv_next;
            if (t + 1 < TT) pv_next = pb[(size_t)(t + 1) * KK + k];
            float c[16];
#pragma unroll
            for (int m = 0; m < 16; ++m)
                c[m] = __shfl(s, hf * 16 + m, 64) + ccol[m];
            float bv = c[0]; int bi = hf * 16;
#pragma unroll
            for (int m = 1; m < 16; ++m) {             // ascending, strict > => first max
                if (c[m] > bv) { bv = c[m]; bi = hf * 16 + m; }
            }
            float ov = __shfl_xor(bv, 32, 64);
            int   oi = __shfl_xor(bi, 32, 64);
            bool take = (ov > bv) || (ov == bv && oi < bi);
            if (take) { bv = ov; bi = oi; }
            if (tid < 32) bp[(t - 1) * KK + k] = (unsigned char)bi;
            s = bv + pv;
        }
        // first-index argmax over final scores
        float bv = s; int bi = k;
#pragma unroll
        for (int d = 16; d >= 1; d >>= 1) {
            float ov = __shfl_xor(bv, d, 64);
            int   oi = __shfl_xor(bi, d, 64);
            bool take = (ov > bv) || (ov == bv && oi < bi);
            if (take) { bv = ov; bi = oi; }
        }
        if (tid == 0) last_tag_s = bi;
    }
    __syncthreads();
    // Phase A: per chunk c (32 steps), chase all 32 candidate entry tags.
    {
        const int k = tid & 31;
        const int cs = tid >> 5;                       // 0..7
        for (int cc = 0; cc < 4; ++cc) {
            const int c = cs * 4 + cc;
            int tag = k;                               // candidate tag at pos c*32+32 (or 1023 for c=31)
            for (int l = 31; l >= 0; --l) {
                const int t = c * 32 + l;
                if (t < TT - 1) tag = bp[t * KK + tag];
                table[(c * 32 + l) * KK + k] = (unsigned char)tag;
            }
        }
    }
    __syncthreads();
    if (tid == 0) {                                    // Phase B: stitch chunk maps
        int e = last_tag_s;
        ent[31] = e;
        for (int c = 30; c >= 0; --c) { e = table[(c + 1) * 32 * KK + e]; ent[c] = e; }
    }
    __syncthreads();
    for (int t = tid; t < TT; t += 256) {              // Phase C: emit (as floats)
        const int c = t >> 5, l = t & 31;
        decoded[(size_t)b * TT + t] = (float)table[(c * 32 + l) * KK + ent[c]];
    }
}

// ---------------------------------------------------------------------------
extern "C" void kernel_launch(void* const* d_in, const int* in_sizes, int n_in,
                              void* d_out, int out_size, void* d_ws, size_t ws_size,
                              hipStream_t stream) {
    const float* X     = (const float*)d_in[0];
    const int*   mask  = (const int*)d_in[1];
    const float* Wk    = (const float*)d_in[2];   // [128,192]
    const float* Wr    = (const float*)d_in[3];   // [64,192]
    const float* gb    = (const float*)d_in[4];   // [2,192]
    const float* Dk    = (const float*)d_in[5];   // [64,32]
    const float* db    = (const float*)d_in[6];   // [32]
    const float* chain = (const float*)d_in[7];   // [32,32]
    const float* lb    = (const float*)d_in[8];
    const float* rb    = (const float*)d_in[9];

    float* out = (float*)d_out;
    float* out_dec  = out;                                   // [B,T]   131072
    float* out_pot  = out + (size_t)BB * TT;                 // [B,T,K] 4194304
    float* out_slen = out + (size_t)BB * TT + (size_t)BB * TT * KK;        // [B]
    float* out_chn  = out_slen + BB;                         // [K,K]

    float* ws = (float*)d_ws;
    float* xp     = ws;                                      // [B*T,192] 25165824 floats
    float* hidden = ws + (size_t)BB * TT * G3;               // [B*T,64]   8388608 floats
    int*   slen_i = (int*)(hidden + (size_t)BB * TT * HH);   // [B]

    xproj_kernel<<<dim3((BB * TT) / XP_ROWS), dim3(G3), 0, stream>>>(X, Wk, gb, xp);
    seqlen_kernel<<<dim3(BB), dim3(256), 0, stream>>>(mask, chain, out_slen, out_chn, slen_i);
    gru_kernel<<<dim3(BB), dim3(G3), 0, stream>>>(xp, Wr, gb, mask, hidden);
    pot_kernel<<<dim3((BB * TT) / PR), dim3(256), 0, stream>>>(hidden, Dk, db, lb, rb, slen_i, out_pot);
    viterbi_kernel<<<dim3(BB), dim3(256), 0, stream>>>(out_pot, chain, out_dec);
}